// Round 2
// baseline (135.945 us; speedup 1.0000x reference)
//
#include <hip/hip_runtime.h>

// Tensor-train per-token contraction:
//   y[t, p,q,o] = relu( bias[p,q,o] + sum_{i,j,k,r,s} a[p,i,r] b[q,j,r,s] c[o,k,s] x[t, i,j,k] )
// x: [65536, 512] (i*64+j*8+k), out: [65536, 1024] (p*128+q*16+o), all fp32.
//
// One PERSISTENT wave handles 8 tokens (grid-stride). Per token, 3 stages:
//   Stage A: lane=(j,k)  t1[p,r] (128 FMA)  -> LDS (8x ds_write_b64)
//   Stage B: lane=(p,k)  t2[q,s] (256 FMA)  -> LDS (8x b64 read + 8x b64 write)
//   Stage C: lane=(q,p)  y[o]    (256 FMA)  -> bias+relu -> 4x dwordx4 store
// No __syncthreads: each wave owns a private 4KB LDS slice; DS ops from one
// wave complete in order, so only compiler barriers (asm memory clobber) are
// needed between phases.
// LDS swizzle (b64 pairs over r/s):
//   T1 (p,r,j,k): dword addr = p*128 + (j^(p&1))*16 + k*2 + r
//   T2 (q,s,p,k): dword addr = q*128 + (k^(q&1))*16 + p*2 + s
// Write side per instr = contiguous 128-dword block (conflict-free);
// read side = flat 4 dwords/bank (the b64 structural floor).

#define NTOK (16 * 4096)
#define NBLK 2048            // 8192 waves, exactly 8 tokens each

__global__ __launch_bounds__(256) void tt_contract_kernel(
    const float* __restrict__ x,
    const float* __restrict__ a,    // [8][8][2]    p,i,r
    const float* __restrict__ b,    // [8][8][2][2] q,j,r,s
    const float* __restrict__ c,    // [16][8][2]   o,k,s
    const float* __restrict__ bias, // [8][8][16]   p,q,o
    float* __restrict__ out)
{
    __shared__ float lds[4][1024];
    const int l  = threadIdx.x & 63;
    const int w  = threadIdx.x >> 6;
    float* buf   = lds[w];
    const int W  = NBLK * 4;
    const int g  = blockIdx.x * 4 + w;

    const int hi = l >> 3;          // stage A: j   | stage B: p | stage C: q
    const int lo = l & 7;           // stage A: k   | stage B: k | stage C: p

    // Lane-invariant bias (stage C role: p=lo, q=hi), hoisted out of the loop.
    float bv[16];
    {
        const float4* bp4 = (const float4*)(bias + (lo * 8 + hi) * 16);
#pragma unroll
        for (int m = 0; m < 4; ++m) {
            float4 t = bp4[m];
            bv[m * 4 + 0] = t.x; bv[m * 4 + 1] = t.y;
            bv[m * 4 + 2] = t.z; bv[m * 4 + 3] = t.w;
        }
    }

    // Preload x for the first token. Lane's x column: x[t*512 + i*64 + l].
    float xi[8];
    {
        const float* xp = x + (size_t)g * 512 + l;
#pragma unroll
        for (int i = 0; i < 8; ++i) xi[i] = xp[i * 64];
    }

    for (int t = g; t < NTOK; t += W) {
        // ---------------- Stage A: lane=(j,k)=(hi,lo) ----------------
#pragma unroll
        for (int p = 0; p < 8; ++p) {
            float a0 = 0.f, a1 = 0.f;
#pragma unroll
            for (int i = 0; i < 8; ++i) {
                a0 = fmaf(a[p * 16 + i * 2 + 0], xi[i], a0);
                a1 = fmaf(a[p * 16 + i * 2 + 1], xi[i], a1);
            }
            *(float2*)(buf + p * 128 + ((hi ^ (p & 1)) << 4) + (lo << 1)) =
                make_float2(a0, a1);
        }
        asm volatile("" ::: "memory");

        // ---------------- Stage B: lane=(p,k)=(hi,lo) ----------------
        float u0[8], u1[8];
#pragma unroll
        for (int j = 0; j < 8; ++j) {
            float2 uu = *(const float2*)(buf + hi * 128 +
                                         ((j ^ (hi & 1)) << 4) + (lo << 1));
            u0[j] = uu.x; u1[j] = uu.y;
        }
        asm volatile("" ::: "memory");

#pragma unroll
        for (int q = 0; q < 8; ++q) {
            float s0 = 0.f, s1 = 0.f;
#pragma unroll
            for (int j = 0; j < 8; ++j) {
                s0 = fmaf(b[q * 32 + j * 4 + 0], u0[j], s0);  // r=0,s=0
                s0 = fmaf(b[q * 32 + j * 4 + 2], u1[j], s0);  // r=1,s=0
                s1 = fmaf(b[q * 32 + j * 4 + 1], u0[j], s1);  // r=0,s=1
                s1 = fmaf(b[q * 32 + j * 4 + 3], u1[j], s1);  // r=1,s=1
            }
            *(float2*)(buf + q * 128 + ((lo ^ (q & 1)) << 4) + (hi << 1)) =
                make_float2(s0, s1);
        }
        asm volatile("" ::: "memory");

        // ---------------- Stage C: lane=(q,p)=(hi,lo) ----------------
        float v0[8], v1[8];
#pragma unroll
        for (int k = 0; k < 8; ++k) {
            float2 vv = *(const float2*)(buf + hi * 128 +
                                         ((k ^ (hi & 1)) << 4) + (lo << 1));
            v0[k] = vv.x; v1[k] = vv.y;
        }
        asm volatile("" ::: "memory");

        // Prefetch next token's x under the stage-C compute.
        const int tn = t + W;
        float xn[8];
        if (tn < NTOK) {
            const float* xp = x + (size_t)tn * 512 + l;
#pragma unroll
            for (int i = 0; i < 8; ++i) xn[i] = xp[i * 64];
        }

        float y[16];
#pragma unroll
        for (int o = 0; o < 16; ++o) {
            float acc = bv[o];
#pragma unroll
            for (int k = 0; k < 8; ++k) {
                acc = fmaf(c[o * 16 + k * 2 + 0], v0[k], acc);
                acc = fmaf(c[o * 16 + k * 2 + 1], v1[k], acc);
            }
            y[o] = acc > 0.f ? acc : 0.f;
        }

        float* op = out + (size_t)t * 1024 + lo * 128 + hi * 16;
#pragma unroll
        for (int m = 0; m < 4; ++m)
            *(float4*)(op + m * 4) = make_float4(y[m * 4 + 0], y[m * 4 + 1],
                                                 y[m * 4 + 2], y[m * 4 + 3]);

#pragma unroll
        for (int i = 0; i < 8; ++i) xi[i] = xn[i];
    }
}

extern "C" void kernel_launch(void* const* d_in, const int* in_sizes, int n_in,
                              void* d_out, int out_size, void* d_ws, size_t ws_size,
                              hipStream_t stream) {
    const float* x    = (const float*)d_in[0];
    const float* a    = (const float*)d_in[1];
    const float* b    = (const float*)d_in[2];
    const float* c    = (const float*)d_in[3];
    const float* bias = (const float*)d_in[4];
    float* out = (float*)d_out;

    tt_contract_kernel<<<NBLK, 256, 0, stream>>>(x, a, b, c, bias, out);
}